// Round 6
// baseline (199.464 us; speedup 1.0000x reference)
//
#include <hip/hip_runtime.h>
#include <math.h>

// Problem constants: B=4,S=4 -> N=16 sequences
#define N_SEQ 16
#define LEN   1024
#define FDIM  256
#define DDIM  256
#define NHEAD 8
#define DHD   32
#define ROWS  (N_SEQ * LEN)          // 16384
#define QSCALE 0.17677669529663687f  // 1/sqrt(32)
#define QKVN  ((size_t)N_SEQ * NHEAD * LEN * DHD)   // 4,194,304 elems

typedef __attribute__((ext_vector_type(8))) short bf16x8;  // 8 bf16 in 4 VGPRs
typedef __attribute__((ext_vector_type(4))) float f32x4;

__device__ __forceinline__ unsigned short f2bf(float f) {
    unsigned int u = __float_as_uint(f);
    unsigned int r = u + 0x7fffu + ((u >> 16) & 1u);   // RNE
    return (unsigned short)(r >> 16);
}

// async global->LDS, 16B per lane; LDS dest = uniform base + lane*16
__device__ __forceinline__ void load_lds16(const void* g, void* l) {
    __builtin_amdgcn_global_load_lds(
        (const __attribute__((address_space(1))) unsigned int*)g,
        (__attribute__((address_space(3))) unsigned int*)l, 16, 0, 0);
}

// ---------------------------------------------------------------------------
// Kernel 0: fp32 -> bf16 convert for X and the 4 weight matrices.
// ---------------------------------------------------------------------------
__global__ __launch_bounds__(256) void convert_bf16(
    const float* __restrict__ X,
    const float* __restrict__ Wq, const float* __restrict__ Wk,
    const float* __restrict__ Wv, const float* __restrict__ Wo,
    unsigned short* __restrict__ Xbf, unsigned short* __restrict__ Wbf)
{
    const size_t idx4 = ((size_t)blockIdx.x * 256 + threadIdx.x) * 4;
    const float* src;
    unsigned short* dst;
    if (idx4 < (size_t)ROWS * FDIM) {
        src = X + idx4;
        dst = Xbf + idx4;
    } else {
        const size_t wi = idx4 - (size_t)ROWS * FDIM;   // [0, 262144)
        const int w = (int)(wi >> 16);
        const size_t off = wi & 65535;
        const float* Ws[4] = {Wq, Wk, Wv, Wo};
        src = Ws[w] + off;
        dst = Wbf + wi;
    }
    float4 v = *(const float4*)src;
    ushort4 u;
    u.x = f2bf(v.x); u.y = f2bf(v.y); u.z = f2bf(v.z); u.w = f2bf(v.w);
    *(ushort4*)dst = u;
}

// ---------------------------------------------------------------------------
// Kernel 1: bf16 MFMA GEMM, 128x128 tile, BK=64, 4 waves, global_load_lds
// staging into FRAGMENT-ORDER LDS: frag (row-group i, ks) = 1 KiB at
// (i*2+ks)*512 elems, lane's 16B at lane*16 (conflict-free b128 both ways).
// MODE 0: QKV epilogue (bias, Q-scale, head-split bf16 scatter).
// MODE 1: out-proj epilogue fused with per-column softmax-pool partials.
// ---------------------------------------------------------------------------
template <int MODE>
__global__ __launch_bounds__(256) void gemm_bf16(
    const unsigned short* __restrict__ Ag, const unsigned short* __restrict__ Bg,
    const float* __restrict__ b0, const float* __restrict__ b1,
    const float* __restrict__ b2,
    unsigned short* __restrict__ OutB,
    float* __restrict__ pmO, float* __restrict__ plO, float* __restrict__ psO)
{
    __shared__ unsigned short As[16 * 512];   // 16 KiB
    __shared__ unsigned short Bs[16 * 512];   // 16 KiB

    const int m0 = blockIdx.x * 128;
    const int n0 = blockIdx.y * 128;
    const int tid  = threadIdx.x;
    const int wv   = tid >> 6;
    const int lane = tid & 63;
    const int l15  = lane & 15;
    const int quad = lane >> 4;
    const int wr = (wv & 1) * 64;
    const int wc = (wv >> 1) * 64;

    // staging role: waves 0,1 -> A frags 0-7/8-15; waves 2,3 -> B likewise
    const int isB = wv >> 1;
    const unsigned short* __restrict__ Mg = isB ? Bg : Ag;
    const int mb0 = isB ? n0 : m0;
    unsigned short* Ms = isB ? Bs : As;
    const int fbase = (wv & 1) * 8;

    f32x4 acc[4][4] = {};

    for (int kt = 0; kt < 4; ++kt) {       // K = 256, BK = 64
        __syncthreads();                   // readers of previous tile done
        #pragma unroll
        for (int f = 0; f < 8; ++f) {
            const int fi = fbase + f;      // 0..15
            const int i = fi >> 1, ks = fi & 1;
            load_lds16(Mg + (size_t)(mb0 + i*16 + l15) * 256 + kt*64 + ks*32 + quad*8,
                       Ms + fi * 512);
        }
        __syncthreads();                   // drains vmcnt (async LDS writes done)
        #pragma unroll
        for (int ks = 0; ks < 2; ++ks) {
            bf16x8 af[4], bfr[4];
            #pragma unroll
            for (int i = 0; i < 4; ++i)
                af[i] = *(const bf16x8*)(&As[((((wv & 1)*4 + i)*2) + ks)*512 + lane*8]);
            #pragma unroll
            for (int j = 0; j < 4; ++j)
                bfr[j] = *(const bf16x8*)(&Bs[((((wv >> 1)*4 + j)*2) + ks)*512 + lane*8]);
            #pragma unroll
            for (int i = 0; i < 4; ++i)
                #pragma unroll
                for (int j = 0; j < 4; ++j)
                    acc[i][j] = __builtin_amdgcn_mfma_f32_16x16x32_bf16(
                        af[i], bfr[j], acc[i][j], 0, 0, 0);
        }
    }

    if (MODE == 0) {
        const int mat = n0 >> 8;
        const float scale = (mat == 0) ? QSCALE : 1.0f;
        const float* __restrict__ bias = (mat == 0) ? b0 : (mat == 1) ? b1 : b2;
        unsigned short* __restrict__ Out = OutB + (size_t)mat * QKVN;
        #pragma unroll
        for (int j = 0; j < 4; ++j) {
            const int c  = n0 + wc + j*16 + l15;
            const int cc = c & 255;
            const int h = cc >> 5, dh = cc & 31;
            const float bv = bias[cc];
            #pragma unroll
            for (int i = 0; i < 4; ++i)
                #pragma unroll
                for (int rr = 0; rr < 4; ++rr) {
                    const int r = m0 + wr + i*16 + quad*4 + rr;
                    const int n = r >> 10, l = r & 1023;
                    Out[(((size_t)(n*NHEAD + h)) * LEN + l) * DHD + dh] =
                        f2bf((acc[i][j][rr] + bv) * scale);
                }
        }
    } else {
        // Fused softmax-pool partials over the block's 128 rows (one n).
        const int n    = blockIdx.x >> 3;
        const int tile = blockIdx.x & 7;
        __shared__ float red[4][64];   // [wave][j*16 + l15]

        float bv[4];
        #pragma unroll
        for (int j = 0; j < 4; ++j) bv[j] = b0[n0 + wc + j*16 + l15];
        #pragma unroll
        for (int i = 0; i < 4; ++i)
            #pragma unroll
            for (int j = 0; j < 4; ++j)
                #pragma unroll
                for (int rr = 0; rr < 4; ++rr)
                    acc[i][j][rr] += bv[j];

        float M[4];
        #pragma unroll
        for (int j = 0; j < 4; ++j) {
            float m = -1e30f;
            #pragma unroll
            for (int i = 0; i < 4; ++i)
                #pragma unroll
                for (int rr = 0; rr < 4; ++rr) m = fmaxf(m, acc[i][j][rr]);
            m = fmaxf(m, __shfl_xor(m, 16));
            m = fmaxf(m, __shfl_xor(m, 32));
            M[j] = m;
        }
        if (quad == 0) {
            #pragma unroll
            for (int j = 0; j < 4; ++j) red[wv][j*16 + l15] = M[j];
        }
        __syncthreads();
        #pragma unroll
        for (int j = 0; j < 4; ++j)
            M[j] = fmaxf(red[wv][j*16 + l15], red[wv^1][j*16 + l15]);
        __syncthreads();

        float LE[4], SE[4];
        #pragma unroll
        for (int j = 0; j < 4; ++j) {
            float le = 0.f, se = 0.f;
            #pragma unroll
            for (int i = 0; i < 4; ++i)
                #pragma unroll
                for (int rr = 0; rr < 4; ++rr) {
                    const float z = acc[i][j][rr];
                    const float e = __expf(z - M[j]);
                    le += e; se += z * e;
                }
            le += __shfl_xor(le, 16); le += __shfl_xor(le, 32);
            se += __shfl_xor(se, 16); se += __shfl_xor(se, 32);
            LE[j] = le; SE[j] = se;
        }
        if (quad == 0) {
            #pragma unroll
            for (int j = 0; j < 4; ++j) red[wv][j*16 + l15] = LE[j];
        }
        __syncthreads();
        float LEp[4];
        #pragma unroll
        for (int j = 0; j < 4; ++j) LEp[j] = red[wv^1][j*16 + l15];
        __syncthreads();
        if (quad == 0) {
            #pragma unroll
            for (int j = 0; j < 4; ++j) red[wv][j*16 + l15] = SE[j];
        }
        __syncthreads();
        float SEp[4];
        #pragma unroll
        for (int j = 0; j < 4; ++j) SEp[j] = red[wv^1][j*16 + l15];

        if ((wv & 1) == 0 && quad == 0) {
            #pragma unroll
            for (int j = 0; j < 4; ++j) {
                const int c = n0 + wc + j*16 + l15;
                const size_t o = ((size_t)n*8 + tile)*256 + c;
                pmO[o] = M[j];
                plO[o] = LE[j] + LEp[j];
                psO[o] = SE[j] + SEp[j];
            }
        }
    }
}

// ---------------------------------------------------------------------------
// Kernel 2: V transpose. Vb[nh][L][32] -> Vtb[nh][32][L].
// ---------------------------------------------------------------------------
__global__ __launch_bounds__(256) void vtrans(
    const unsigned short* __restrict__ Vb, unsigned short* __restrict__ Vtb)
{
    __shared__ unsigned short Ls[64 * 34];

    const int nh = blockIdx.y;
    const int l0 = blockIdx.x * 64;
    const int tid = threadIdx.x;

    const int row = tid >> 2, c8 = (tid & 3) * 8;
    *(bf16x8*)(&Ls[row*34 + c8]) =
        *(const bf16x8*)(Vb + ((size_t)nh * LEN + l0 + row) * DHD + c8);
    __syncthreads();

    const int dh = tid >> 3, l8 = (tid & 7) * 8;
    ushort4 u0, u1;
    u0.x = Ls[(l8+0)*34 + dh]; u0.y = Ls[(l8+1)*34 + dh];
    u0.z = Ls[(l8+2)*34 + dh]; u0.w = Ls[(l8+3)*34 + dh];
    u1.x = Ls[(l8+4)*34 + dh]; u1.y = Ls[(l8+5)*34 + dh];
    u1.z = Ls[(l8+6)*34 + dh]; u1.w = Ls[(l8+7)*34 + dh];
    unsigned short* dst = Vtb + ((size_t)nh * DHD + dh) * LEN + l0 + l8;
    *(ushort4*)(dst)     = u0;
    *(ushort4*)(dst + 4) = u1;
}

// ---------------------------------------------------------------------------
// Kernel 3: MFMA flash attention, fixed-max softmax, NO K/V LDS staging:
// K B-frags and Vt A-frags load straight from global (coalesced 16B/lane,
// L2-resident), so the main loop has ZERO barriers. Only the wave-private
// P round-trip uses LDS. K frags prefetched one 64-key step ahead.
// ---------------------------------------------------------------------------
#define LDPb 72    // P leading dim bf16 (64 data + 8 pad)
__global__ __launch_bounds__(256) void attn_mfma(
    const unsigned short* __restrict__ Qg_, const unsigned short* __restrict__ Kg_,
    const unsigned short* __restrict__ Vg_, unsigned short* __restrict__ Aout)
{
    __shared__ unsigned short Pb[4][16 * LDPb]; // 9216 B
    __shared__ float stats[4][16];

    const int nh = blockIdx.y;
    const int n  = nh >> 3, h = nh & 7;
    const int q0 = blockIdx.x * 64;
    const int tid  = threadIdx.x;
    const int wv   = tid >> 6;
    const int lane = tid & 63;
    const int l15  = lane & 15;
    const int quad = lane >> 4;

    const unsigned short* __restrict__ Qg = Qg_ + (size_t)nh * LEN * DHD;
    const unsigned short* __restrict__ Kg = Kg_ + (size_t)nh * LEN * DHD;
    const unsigned short* __restrict__ Vg = Vg_ + (size_t)nh * DHD * LEN;

    bf16x8 qf = *(const bf16x8*)(Qg + (size_t)(q0 + wv*16 + l15) * DHD + quad*8);

    // per-lane row pointers for direct-from-global fragments
    const unsigned short* __restrict__ krow = Kg + (size_t)l15 * DHD + quad*8;
    const unsigned short* __restrict__ varow = Vg + (size_t)l15 * LEN;
    const unsigned short* __restrict__ vbrow = Vg + (size_t)(16 + l15) * LEN;

    f32x4 o0 = {0.f, 0.f, 0.f, 0.f};   // O^T[d=quad*4+r][q=l15], d 0..15
    f32x4 o1 = {0.f, 0.f, 0.f, 0.f};   // d 16..31
    float l_lane[4] = {0.f, 0.f, 0.f, 0.f};

    unsigned short* __restrict__ Pw = &Pb[wv][0];

    // prefetch K frags for kb=0
    bf16x8 kf[4];
    #pragma unroll
    for (int sub = 0; sub < 4; ++sub)
        kf[sub] = *(const bf16x8*)(krow + (size_t)(sub*16) * DHD);

    for (int kb = 0; kb < 16; ++kb) {
        const int k0 = kb * 64;
        // QK^T: 4 subtiles of 16 keys
        f32x4 s[4];
        #pragma unroll
        for (int sub = 0; sub < 4; ++sub) {
            f32x4 z = {0.f, 0.f, 0.f, 0.f};
            s[sub] = __builtin_amdgcn_mfma_f32_16x16x32_bf16(qf, kf[sub], z, 0, 0, 0);
        }
        // prefetch next K frags (uniform branch)
        if (kb < 15) {
            #pragma unroll
            for (int sub = 0; sub < 4; ++sub)
                kf[sub] = *(const bf16x8*)(krow + (size_t)(k0 + 64 + sub*16) * DHD);
        }
        // fixed-max softmax: p = exp(s); l per-lane; P -> wave-private LDS bf16
        #pragma unroll
        for (int sub = 0; sub < 4; ++sub)
            #pragma unroll
            for (int r = 0; r < 4; ++r) {
                const float p = __expf(s[sub][r]);
                l_lane[r] += p;
                Pw[(quad*4 + r)*LDPb + sub*16 + l15] = f2bf(p);
            }
        // O^T += Vt-rows x P-rows (V frags direct from global)
        #pragma unroll
        for (int kk = 0; kk < 2; ++kk) {
            bf16x8 pf = *(const bf16x8*)(&Pw[l15*LDPb + kk*32 + quad*8]);
            bf16x8 va = *(const bf16x8*)(varow + k0 + kk*32 + quad*8);
            bf16x8 vb = *(const bf16x8*)(vbrow + k0 + kk*32 + quad*8);
            o0 = __builtin_amdgcn_mfma_f32_16x16x32_bf16(va, pf, o0, 0, 0, 0);
            o1 = __builtin_amdgcn_mfma_f32_16x16x32_bf16(vb, pf, o1, 0, 0, 0);
        }
    }

    // reduce l across the 16 lanes of each quad-row
    #pragma unroll
    for (int r = 0; r < 4; ++r) {
        float t = l_lane[r];
        t += __shfl_xor(t, 1);
        t += __shfl_xor(t, 2);
        t += __shfl_xor(t, 4);
        t += __shfl_xor(t, 8);
        l_lane[r] = t;
    }
    __syncthreads();
    if (l15 == 0) {
        #pragma unroll
        for (int r = 0; r < 4; ++r) stats[wv][quad*4 + r] = l_lane[r];
    }
    __syncthreads();
    const float linv = 1.f / stats[wv][l15];

    // transpose O^T -> O through (reused) wave-private LDS, bf16 store
    float* __restrict__ Tw = (float*)&Pb[wv][0];   // 16 x 36 fp32 = 2304 B
    #pragma unroll
    for (int r = 0; r < 4; ++r) {
        Tw[l15*36 + quad*4 + r]      = o0[r] * linv;
        Tw[l15*36 + 16 + quad*4 + r] = o1[r] * linv;
    }
    __syncthreads();
    const int qr = lane >> 2, c8 = (lane & 3) * 8;
    float4 r0 = *(const float4*)(&Tw[qr*36 + c8]);
    float4 r1 = *(const float4*)(&Tw[qr*36 + c8 + 4]);
    unsigned short* dst = Aout + ((size_t)(n*LEN + q0 + wv*16 + qr)) * DDIM + h*DHD + c8;
    ushort4 u0, u1;
    u0.x = f2bf(r0.x); u0.y = f2bf(r0.y); u0.z = f2bf(r0.z); u0.w = f2bf(r0.w);
    u1.x = f2bf(r1.x); u1.y = f2bf(r1.y); u1.z = f2bf(r1.z); u1.w = f2bf(r1.w);
    *(ushort4*)(dst)     = u0;
    *(ushort4*)(dst + 4) = u1;
}

// ---------------------------------------------------------------------------
// Kernel 4: merge 8 per-tile pool partials per (n,d), write [B,S,D] output.
// ---------------------------------------------------------------------------
__global__ __launch_bounds__(256) void pool_merge(
    const float* __restrict__ pm, const float* __restrict__ pl,
    const float* __restrict__ ps, float* __restrict__ out)
{
    const int n = blockIdx.x;
    const int d = threadIdx.x;
    float M = -1e30f;
    #pragma unroll
    for (int t = 0; t < 8; ++t) M = fmaxf(M, pm[((size_t)n*8 + t)*256 + d]);
    float L = 0.f, S = 0.f;
    #pragma unroll
    for (int t = 0; t < 8; ++t) {
        const size_t idx = ((size_t)n*8 + t)*256 + d;
        const float w = __expf(pm[idx] - M);
        L += pl[idx] * w;
        S += ps[idx] * w;
    }
    out[n*256 + d] = S / L;
}

// ---------------------------------------------------------------------------
extern "C" void kernel_launch(void* const* d_in, const int* in_sizes, int n_in,
                              void* d_out, int out_size, void* d_ws, size_t ws_size,
                              hipStream_t stream)
{
    const float* x  = (const float*)d_in[0];
    const float* Wq = (const float*)d_in[1];
    const float* bq = (const float*)d_in[2];
    const float* Wk = (const float*)d_in[3];
    const float* bk = (const float*)d_in[4];
    const float* Wv = (const float*)d_in[5];
    const float* bv = (const float*)d_in[6];
    const float* Wo = (const float*)d_in[7];
    const float* bo = (const float*)d_in[8];
    float* out = (float*)d_out;

    char* base = (char*)d_ws;
    unsigned short* Xbf  = (unsigned short*)(base);                 //  8,388,608 B
    unsigned short* Qb   = (unsigned short*)(base +  8388608);      //  8,388,608
    unsigned short* Kb   = (unsigned short*)(base + 16777216);      //  8,388,608
    unsigned short* Vb   = (unsigned short*)(base + 25165824);      //  8,388,608
    unsigned short* Vtb  = (unsigned short*)(base + 33554432);      //  8,388,608
    unsigned short* attnb= (unsigned short*)(base + 41943040);      //  8,388,608
    unsigned short* Wbf  = (unsigned short*)(base + 50331648);      //    524,288
    float* pm = (float*)(base + 50855936);                          //    131,072
    float* pl = (float*)(base + 50987008);                          //    131,072
    float* ps = (float*)(base + 51118080);                          //    131,072
    const size_t need_bytes = 51249152;
    if (ws_size < need_bytes) return;

    convert_bf16<<<4352, 256, 0, stream>>>(x, Wq, Wk, Wv, Wo, Xbf, Wbf);
    gemm_bf16<0><<<dim3(ROWS/128, 6), 256, 0, stream>>>(
        Xbf, Wbf, bq, bk, bv, Qb, nullptr, nullptr, nullptr);
    vtrans<<<dim3(LEN/64, N_SEQ*NHEAD), 256, 0, stream>>>(Vb, Vtb);
    attn_mfma<<<dim3(LEN/64, N_SEQ*NHEAD), 256, 0, stream>>>(Qb, Kb, Vtb, attnb);
    gemm_bf16<1><<<dim3(ROWS/128, 2), 256, 0, stream>>>(
        attnb, Wbf + (size_t)768*256, bo, nullptr, nullptr, nullptr, pm, pl, ps);
    pool_merge<<<16, 256, 0, stream>>>(pm, pl, ps, out);
}

// Round 7
// 159.812 us; speedup vs baseline: 1.2481x; 1.2481x over previous
//
#include <hip/hip_runtime.h>
#include <math.h>

// Problem constants: B=4,S=4 -> N=16 sequences
#define N_SEQ 16
#define LEN   1024
#define FDIM  256
#define DDIM  256
#define NHEAD 8
#define DHD   32
#define ROWS  (N_SEQ * LEN)          // 16384
#define QSCALE 0.17677669529663687f  // 1/sqrt(32)
#define QKVN  ((size_t)N_SEQ * NHEAD * LEN * DHD)   // 4,194,304 elems

typedef __attribute__((ext_vector_type(8))) short bf16x8;  // 8 bf16 in 4 VGPRs
typedef __attribute__((ext_vector_type(4))) float f32x4;

__device__ __forceinline__ unsigned short f2bf(float f) {
    unsigned int u = __float_as_uint(f);
    unsigned int r = u + 0x7fffu + ((u >> 16) & 1u);   // RNE
    return (unsigned short)(r >> 16);
}

// async global->LDS, 16B per lane; LDS dest = uniform base + lane*16
__device__ __forceinline__ void load_lds16(const void* g, void* l) {
    __builtin_amdgcn_global_load_lds(
        (const __attribute__((address_space(1))) unsigned int*)g,
        (__attribute__((address_space(3))) unsigned int*)l, 16, 0, 0);
}

// ---------------------------------------------------------------------------
// Kernel 0: fp32 -> bf16 convert for X and the 4 weight matrices.
// ---------------------------------------------------------------------------
__global__ __launch_bounds__(256) void convert_bf16(
    const float* __restrict__ X,
    const float* __restrict__ Wq, const float* __restrict__ Wk,
    const float* __restrict__ Wv, const float* __restrict__ Wo,
    unsigned short* __restrict__ Xbf, unsigned short* __restrict__ Wbf)
{
    const size_t idx4 = ((size_t)blockIdx.x * 256 + threadIdx.x) * 4;
    const float* src;
    unsigned short* dst;
    if (idx4 < (size_t)ROWS * FDIM) {
        src = X + idx4;
        dst = Xbf + idx4;
    } else {
        const size_t wi = idx4 - (size_t)ROWS * FDIM;   // [0, 262144)
        const int w = (int)(wi >> 16);
        const size_t off = wi & 65535;
        const float* Ws[4] = {Wq, Wk, Wv, Wo};
        src = Ws[w] + off;
        dst = Wbf + wi;
    }
    float4 v = *(const float4*)src;
    ushort4 u;
    u.x = f2bf(v.x); u.y = f2bf(v.y); u.z = f2bf(v.z); u.w = f2bf(v.w);
    *(ushort4*)dst = u;
}

// ---------------------------------------------------------------------------
// Kernel 1: bf16 MFMA GEMM, 128x128 tile, BK=64, 4 waves, global_load_lds
// staging into fragment-order LDS (R6-verified).
// MODE 0: QKV epilogue (bias, Q-scale, head-split bf16 scatter).
// MODE 1: out-proj epilogue fused with per-column softmax-pool partials.
// ---------------------------------------------------------------------------
template <int MODE>
__global__ __launch_bounds__(256) void gemm_bf16(
    const unsigned short* __restrict__ Ag, const unsigned short* __restrict__ Bg,
    const float* __restrict__ b0, const float* __restrict__ b1,
    const float* __restrict__ b2,
    unsigned short* __restrict__ OutB,
    float* __restrict__ pmO, float* __restrict__ plO, float* __restrict__ psO)
{
    __shared__ unsigned short As[16 * 512];   // 16 KiB
    __shared__ unsigned short Bs[16 * 512];   // 16 KiB

    const int m0 = blockIdx.x * 128;
    const int n0 = blockIdx.y * 128;
    const int tid  = threadIdx.x;
    const int wv   = tid >> 6;
    const int lane = tid & 63;
    const int l15  = lane & 15;
    const int quad = lane >> 4;
    const int wr = (wv & 1) * 64;
    const int wc = (wv >> 1) * 64;

    // staging role: waves 0,1 -> A frags 0-7/8-15; waves 2,3 -> B likewise
    const int isB = wv >> 1;
    const unsigned short* __restrict__ Mg = isB ? Bg : Ag;
    const int mb0 = isB ? n0 : m0;
    unsigned short* Ms = isB ? Bs : As;
    const int fbase = (wv & 1) * 8;

    f32x4 acc[4][4] = {};

    for (int kt = 0; kt < 4; ++kt) {       // K = 256, BK = 64
        __syncthreads();                   // readers of previous tile done
        #pragma unroll
        for (int f = 0; f < 8; ++f) {
            const int fi = fbase + f;      // 0..15
            const int i = fi >> 1, ks = fi & 1;
            load_lds16(Mg + (size_t)(mb0 + i*16 + l15) * 256 + kt*64 + ks*32 + quad*8,
                       Ms + fi * 512);
        }
        __syncthreads();                   // drains vmcnt (async LDS writes done)
        #pragma unroll
        for (int ks = 0; ks < 2; ++ks) {
            bf16x8 af[4], bfr[4];
            #pragma unroll
            for (int i = 0; i < 4; ++i)
                af[i] = *(const bf16x8*)(&As[((((wv & 1)*4 + i)*2) + ks)*512 + lane*8]);
            #pragma unroll
            for (int j = 0; j < 4; ++j)
                bfr[j] = *(const bf16x8*)(&Bs[((((wv >> 1)*4 + j)*2) + ks)*512 + lane*8]);
            #pragma unroll
            for (int i = 0; i < 4; ++i)
                #pragma unroll
                for (int j = 0; j < 4; ++j)
                    acc[i][j] = __builtin_amdgcn_mfma_f32_16x16x32_bf16(
                        af[i], bfr[j], acc[i][j], 0, 0, 0);
        }
    }

    if (MODE == 0) {
        const int mat = n0 >> 8;
        const float scale = (mat == 0) ? QSCALE : 1.0f;
        const float* __restrict__ bias = (mat == 0) ? b0 : (mat == 1) ? b1 : b2;
        unsigned short* __restrict__ Out = OutB + (size_t)mat * QKVN;
        #pragma unroll
        for (int j = 0; j < 4; ++j) {
            const int c  = n0 + wc + j*16 + l15;
            const int cc = c & 255;
            const int h = cc >> 5, dh = cc & 31;
            const float bv = bias[cc];
            #pragma unroll
            for (int i = 0; i < 4; ++i)
                #pragma unroll
                for (int rr = 0; rr < 4; ++rr) {
                    const int r = m0 + wr + i*16 + quad*4 + rr;
                    const int n = r >> 10, l = r & 1023;
                    Out[(((size_t)(n*NHEAD + h)) * LEN + l) * DHD + dh] =
                        f2bf((acc[i][j][rr] + bv) * scale);
                }
        }
    } else {
        // Fused softmax-pool partials over the block's 128 rows (one n).
        const int n    = blockIdx.x >> 3;
        const int tile = blockIdx.x & 7;
        __shared__ float red[4][64];   // [wave][j*16 + l15]

        float bv[4];
        #pragma unroll
        for (int j = 0; j < 4; ++j) bv[j] = b0[n0 + wc + j*16 + l15];
        #pragma unroll
        for (int i = 0; i < 4; ++i)
            #pragma unroll
            for (int j = 0; j < 4; ++j)
                #pragma unroll
                for (int rr = 0; rr < 4; ++rr)
                    acc[i][j][rr] += bv[j];

        float M[4];
        #pragma unroll
        for (int j = 0; j < 4; ++j) {
            float m = -1e30f;
            #pragma unroll
            for (int i = 0; i < 4; ++i)
                #pragma unroll
                for (int rr = 0; rr < 4; ++rr) m = fmaxf(m, acc[i][j][rr]);
            m = fmaxf(m, __shfl_xor(m, 16));
            m = fmaxf(m, __shfl_xor(m, 32));
            M[j] = m;
        }
        if (quad == 0) {
            #pragma unroll
            for (int j = 0; j < 4; ++j) red[wv][j*16 + l15] = M[j];
        }
        __syncthreads();
        #pragma unroll
        for (int j = 0; j < 4; ++j)
            M[j] = fmaxf(red[wv][j*16 + l15], red[wv^1][j*16 + l15]);
        __syncthreads();

        float LE[4], SE[4];
        #pragma unroll
        for (int j = 0; j < 4; ++j) {
            float le = 0.f, se = 0.f;
            #pragma unroll
            for (int i = 0; i < 4; ++i)
                #pragma unroll
                for (int rr = 0; rr < 4; ++rr) {
                    const float z = acc[i][j][rr];
                    const float e = __expf(z - M[j]);
                    le += e; se += z * e;
                }
            le += __shfl_xor(le, 16); le += __shfl_xor(le, 32);
            se += __shfl_xor(se, 16); se += __shfl_xor(se, 32);
            LE[j] = le; SE[j] = se;
        }
        if (quad == 0) {
            #pragma unroll
            for (int j = 0; j < 4; ++j) red[wv][j*16 + l15] = LE[j];
        }
        __syncthreads();
        float LEp[4];
        #pragma unroll
        for (int j = 0; j < 4; ++j) LEp[j] = red[wv^1][j*16 + l15];
        __syncthreads();
        if (quad == 0) {
            #pragma unroll
            for (int j = 0; j < 4; ++j) red[wv][j*16 + l15] = SE[j];
        }
        __syncthreads();
        float SEp[4];
        #pragma unroll
        for (int j = 0; j < 4; ++j) SEp[j] = red[wv^1][j*16 + l15];

        if ((wv & 1) == 0 && quad == 0) {
            #pragma unroll
            for (int j = 0; j < 4; ++j) {
                const int c = n0 + wc + j*16 + l15;
                const size_t o = ((size_t)n*8 + tile)*256 + c;
                pmO[o] = M[j];
                plO[o] = LE[j] + LEp[j];
                psO[o] = SE[j] + SEp[j];
            }
        }
    }
}

// ---------------------------------------------------------------------------
// Kernel 2: V transpose. Vb[nh][L][32] -> Vtb[nh][32][L].
// ---------------------------------------------------------------------------
__global__ __launch_bounds__(256) void vtrans(
    const unsigned short* __restrict__ Vb, unsigned short* __restrict__ Vtb)
{
    __shared__ unsigned short Ls[64 * 34];

    const int nh = blockIdx.y;
    const int l0 = blockIdx.x * 64;
    const int tid = threadIdx.x;

    const int row = tid >> 2, c8 = (tid & 3) * 8;
    *(bf16x8*)(&Ls[row*34 + c8]) =
        *(const bf16x8*)(Vb + ((size_t)nh * LEN + l0 + row) * DHD + c8);
    __syncthreads();

    const int dh = tid >> 3, l8 = (tid & 7) * 8;
    ushort4 u0, u1;
    u0.x = Ls[(l8+0)*34 + dh]; u0.y = Ls[(l8+1)*34 + dh];
    u0.z = Ls[(l8+2)*34 + dh]; u0.w = Ls[(l8+3)*34 + dh];
    u1.x = Ls[(l8+4)*34 + dh]; u1.y = Ls[(l8+5)*34 + dh];
    u1.z = Ls[(l8+6)*34 + dh]; u1.w = Ls[(l8+7)*34 + dh];
    unsigned short* dst = Vtb + ((size_t)nh * DHD + dh) * LEN + l0 + l8;
    *(ushort4*)(dst)     = u0;
    *(ushort4*)(dst + 4) = u1;
}

// ---------------------------------------------------------------------------
// Kernel 3: MFMA flash attention, fixed-max softmax, S^T formulation:
//   S^T = K.Q^T (A=K rows, B=Q rows) -> C-layout holds P^T with
//   q = lane&15, key = quad*4+r. P^T writes to wave-private LDS are 4
//   packed ds_write_b64 per 64 keys (B-frag order), softmax denominator
//   is a single per-lane scalar (reduced with 2 shuffles at the end).
//   K/V LDS-staged 128 keys/round (R5 structure, R6's no-staging regressed).
// ---------------------------------------------------------------------------
#define LDK2 40    // Ks leading dim bf16 (32 data + 8 pad)
#define LDV2 136   // Vs leading dim bf16 (128 data + 8 pad)
#define LDPk 72    // P^T leading dim bf16 (64 data + 8 pad; 16B-aligned rows)
__global__ __launch_bounds__(256) void attn_mfma(
    const unsigned short* __restrict__ Qg_, const unsigned short* __restrict__ Kg_,
    const unsigned short* __restrict__ Vg_, unsigned short* __restrict__ Aout)
{
    __shared__ unsigned short Ks[128 * LDK2];   // 10240 B
    __shared__ unsigned short Vs[32 * LDV2];    //  8704 B
    __shared__ unsigned short Pb[4][16 * LDPk]; //  9216 B

    const int nh = blockIdx.y;
    const int n  = nh >> 3, h = nh & 7;
    const int q0 = blockIdx.x * 64;
    const int tid  = threadIdx.x;
    const int wv   = tid >> 6;
    const int lane = tid & 63;
    const int l15  = lane & 15;
    const int quad = lane >> 4;

    const unsigned short* __restrict__ Qg = Qg_ + (size_t)nh * LEN * DHD;
    const unsigned short* __restrict__ Kg = Kg_ + (size_t)nh * LEN * DHD;
    const unsigned short* __restrict__ Vg = Vg_ + (size_t)nh * DHD * LEN;

    // Q fragment (B-operand now): row q0+wv*16+l15, k = quad*8 + j
    bf16x8 qf = *(const bf16x8*)(Qg + (size_t)(q0 + wv*16 + l15) * DHD + quad*8);

    f32x4 o0 = {0.f, 0.f, 0.f, 0.f};   // O^T[d=quad*4+r][q=l15], d 0..15
    f32x4 o1 = {0.f, 0.f, 0.f, 0.f};   // d 16..31
    float l_lane = 0.f;                // sum of exp for q=l15 over this lane's keys

    const int krow = tid >> 2, kc8 = (tid & 3) * 8;  // K: 128 rows x 32
    const int vrow = tid >> 3, vc8 = (tid & 7) * 8;  // V: 32 rows x 128

    unsigned short* __restrict__ Pw = &Pb[wv][0];

    for (int kt = 0; kt < LEN / 128; ++kt) {   // 8 staging rounds
        const int k0 = kt * 128;
        __syncthreads();
        *(bf16x8*)(&Ks[krow*LDK2 + kc8]) =
            *(const bf16x8*)(Kg + (size_t)(k0 + krow)*DHD + kc8);
        *(bf16x8*)(&Ks[(64 + krow)*LDK2 + kc8]) =
            *(const bf16x8*)(Kg + (size_t)(k0 + 64 + krow)*DHD + kc8);
        *(bf16x8*)(&Vs[vrow*LDV2 + vc8]) =
            *(const bf16x8*)(Vg + (size_t)vrow*LEN + k0 + vc8);
        *(bf16x8*)(&Vs[vrow*LDV2 + 64 + vc8]) =
            *(const bf16x8*)(Vg + (size_t)vrow*LEN + k0 + 64 + vc8);
        __syncthreads();

        #pragma unroll
        for (int half = 0; half < 2; ++half) {
            // S^T = K.Q^T: 4 subtiles of 16 keys (A = K rows, B = Q rows)
            f32x4 st[4];
            #pragma unroll
            for (int sub = 0; sub < 4; ++sub) {
                bf16x8 kf = *(const bf16x8*)(&Ks[(half*64 + sub*16 + l15)*LDK2 + quad*8]);
                f32x4 z = {0.f, 0.f, 0.f, 0.f};
                st[sub] = __builtin_amdgcn_mfma_f32_16x16x32_bf16(kf, qf, z, 0, 0, 0);
            }
            // p = exp(s); scalar l accumulate; packed b64 write in B-frag order
            #pragma unroll
            for (int sub = 0; sub < 4; ++sub) {
                const float p0 = __expf(st[sub][0]);
                const float p1 = __expf(st[sub][1]);
                const float p2 = __expf(st[sub][2]);
                const float p3 = __expf(st[sub][3]);
                l_lane += (p0 + p1) + (p2 + p3);
                uint2 pk;
                pk.x = (unsigned int)f2bf(p0) | ((unsigned int)f2bf(p1) << 16);
                pk.y = (unsigned int)f2bf(p2) | ((unsigned int)f2bf(p3) << 16);
                *(uint2*)(&Pw[l15*LDPk + sub*16 + quad*4]) = pk;
            }
            // O^T += Vt-rows x P^T-rows (wave-private P; in-order LDS)
            #pragma unroll
            for (int kk = 0; kk < 2; ++kk) {
                bf16x8 pf = *(const bf16x8*)(&Pw[l15*LDPk + kk*32 + quad*8]);
                bf16x8 va = *(const bf16x8*)(&Vs[l15*LDV2 + half*64 + kk*32 + quad*8]);
                bf16x8 vb = *(const bf16x8*)(&Vs[(16 + l15)*LDV2 + half*64 + kk*32 + quad*8]);
                o0 = __builtin_amdgcn_mfma_f32_16x16x32_bf16(va, pf, o0, 0, 0, 0);
                o1 = __builtin_amdgcn_mfma_f32_16x16x32_bf16(vb, pf, o1, 0, 0, 0);
            }
        }
    }

    // reduce l across the 4 quad-lanes holding q=l15
    l_lane += __shfl_xor(l_lane, 16);
    l_lane += __shfl_xor(l_lane, 32);
    const float linv = 1.f / l_lane;

    // transpose O^T -> O through wave-private LDS, bf16 store
    float* __restrict__ Tw = (float*)&Pb[wv][0];   // 16 x 36 fp32 = 2304 B
    #pragma unroll
    for (int r = 0; r < 4; ++r) {
        Tw[l15*36 + quad*4 + r]      = o0[r] * linv;
        Tw[l15*36 + 16 + quad*4 + r] = o1[r] * linv;
    }
    __syncthreads();
    const int qr = lane >> 2, c8 = (lane & 3) * 8;
    float4 r0 = *(const float4*)(&Tw[qr*36 + c8]);
    float4 r1 = *(const float4*)(&Tw[qr*36 + c8 + 4]);
    unsigned short* dst = Aout + ((size_t)(n*LEN + q0 + wv*16 + qr)) * DDIM + h*DHD + c8;
    ushort4 u0, u1;
    u0.x = f2bf(r0.x); u0.y = f2bf(r0.y); u0.z = f2bf(r0.z); u0.w = f2bf(r0.w);
    u1.x = f2bf(r1.x); u1.y = f2bf(r1.y); u1.z = f2bf(r1.z); u1.w = f2bf(r1.w);
    *(ushort4*)(dst)     = u0;
    *(ushort4*)(dst + 4) = u1;
}

// ---------------------------------------------------------------------------
// Kernel 4: merge 8 per-tile pool partials per (n,d), write [B,S,D] output.
// ---------------------------------------------------------------------------
__global__ __launch_bounds__(256) void pool_merge(
    const float* __restrict__ pm, const float* __restrict__ pl,
    const float* __restrict__ ps, float* __restrict__ out)
{
    const int n = blockIdx.x;
    const int d = threadIdx.x;
    float M = -1e30f;
    #pragma unroll
    for (int t = 0; t < 8; ++t) M = fmaxf(M, pm[((size_t)n*8 + t)*256 + d]);
    float L = 0.f, S = 0.f;
    #pragma unroll
    for (int t = 0; t < 8; ++t) {
        const size_t idx = ((size_t)n*8 + t)*256 + d;
        const float w = __expf(pm[idx] - M);
        L += pl[idx] * w;
        S += ps[idx] * w;
    }
    out[n*256 + d] = S / L;
}

// ---------------------------------------------------------------------------
extern "C" void kernel_launch(void* const* d_in, const int* in_sizes, int n_in,
                              void* d_out, int out_size, void* d_ws, size_t ws_size,
                              hipStream_t stream)
{
    const float* x  = (const float*)d_in[0];
    const float* Wq = (const float*)d_in[1];
    const float* bq = (const float*)d_in[2];
    const float* Wk = (const float*)d_in[3];
    const float* bk = (const float*)d_in[4];
    const float* Wv = (const float*)d_in[5];
    const float* bv = (const float*)d_in[6];
    const float* Wo = (const float*)d_in[7];
    const float* bo = (const float*)d_in[8];
    float* out = (float*)d_out;

    char* base = (char*)d_ws;
    unsigned short* Xbf  = (unsigned short*)(base);                 //  8,388,608 B
    unsigned short* Qb   = (unsigned short*)(base +  8388608);      //  8,388,608
    unsigned short* Kb   = (unsigned short*)(base + 16777216);      //  8,388,608
    unsigned short* Vb   = (unsigned short*)(base + 25165824);      //  8,388,608
    unsigned short* Vtb  = (unsigned short*)(base + 33554432);      //  8,388,608
    unsigned short* attnb= (unsigned short*)(base + 41943040);      //  8,388,608
    unsigned short* Wbf  = (unsigned short*)(base + 50331648);      //    524,288
    float* pm = (float*)(base + 50855936);                          //    131,072
    float* pl = (float*)(base + 50987008);                          //    131,072
    float* ps = (float*)(base + 51118080);                          //    131,072
    const size_t need_bytes = 51249152;
    if (ws_size < need_bytes) return;

    convert_bf16<<<4352, 256, 0, stream>>>(x, Wq, Wk, Wv, Wo, Xbf, Wbf);
    gemm_bf16<0><<<dim3(ROWS/128, 6), 256, 0, stream>>>(
        Xbf, Wbf, bq, bk, bv, Qb, nullptr, nullptr, nullptr);
    vtrans<<<dim3(LEN/64, N_SEQ*NHEAD), 256, 0, stream>>>(Vb, Vtb);
    attn_mfma<<<dim3(LEN/64, N_SEQ*NHEAD), 256, 0, stream>>>(Qb, Kb, Vtb, attnb);
    gemm_bf16<1><<<dim3(ROWS/128, 2), 256, 0, stream>>>(
        attnb, Wbf + (size_t)768*256, bo, nullptr, nullptr, nullptr, pm, pl, ps);
    pool_merge<<<16, 256, 0, stream>>>(pm, pl, ps, out);
}

// Round 8
// 140.843 us; speedup vs baseline: 1.4162x; 1.1347x over previous
//
#include <hip/hip_runtime.h>
#include <math.h>

// Problem constants: B=4,S=4 -> N=16 sequences
#define N_SEQ 16
#define LEN   1024
#define FDIM  256
#define DDIM  256
#define NHEAD 8
#define DHD   32
#define ROWS  (N_SEQ * LEN)          // 16384
#define QSCALE 0.17677669529663687f  // 1/sqrt(32)
#define QKVN  ((size_t)N_SEQ * NHEAD * LEN * DHD)   // 4,194,304 elems

typedef __attribute__((ext_vector_type(8))) short bf16x8;  // 8 bf16 in 4 VGPRs
typedef __attribute__((ext_vector_type(4))) float f32x4;

__device__ __forceinline__ unsigned short f2bf(float f) {
    unsigned int u = __float_as_uint(f);
    unsigned int r = u + 0x7fffu + ((u >> 16) & 1u);   // RNE
    return (unsigned short)(r >> 16);
}

// async global->LDS, 16B per lane; LDS dest = uniform base + lane*16
__device__ __forceinline__ void load_lds16(const void* g, void* l) {
    __builtin_amdgcn_global_load_lds(
        (const __attribute__((address_space(1))) unsigned int*)g,
        (__attribute__((address_space(3))) unsigned int*)l, 16, 0, 0);
}

// ---------------------------------------------------------------------------
// Kernel 0: fp32 -> bf16 convert for X and the 4 weight matrices.
// ---------------------------------------------------------------------------
__global__ __launch_bounds__(256) void convert_bf16(
    const float* __restrict__ X,
    const float* __restrict__ Wq, const float* __restrict__ Wk,
    const float* __restrict__ Wv, const float* __restrict__ Wo,
    unsigned short* __restrict__ Xbf, unsigned short* __restrict__ Wbf)
{
    const size_t idx4 = ((size_t)blockIdx.x * 256 + threadIdx.x) * 4;
    const float* src;
    unsigned short* dst;
    if (idx4 < (size_t)ROWS * FDIM) {
        src = X + idx4;
        dst = Xbf + idx4;
    } else {
        const size_t wi = idx4 - (size_t)ROWS * FDIM;   // [0, 262144)
        const int w = (int)(wi >> 16);
        const size_t off = wi & 65535;
        const float* Ws[4] = {Wq, Wk, Wv, Wo};
        src = Ws[w] + off;
        dst = Wbf + wi;
    }
    float4 v = *(const float4*)src;
    ushort4 u;
    u.x = f2bf(v.x); u.y = f2bf(v.y); u.z = f2bf(v.z); u.w = f2bf(v.w);
    *(ushort4*)dst = u;
}

// ---------------------------------------------------------------------------
// Kernel 1: bf16 MFMA GEMM, 128x128 tile, BK=64, 4 waves, global_load_lds
// staging into fragment-order LDS (R6-verified).
// MODE 0: QKV epilogue. Q,K: bias (+Q-scale) head-split scatter.
//         V: written directly in PV A-FRAGMENT order (vtrans eliminated):
//         Vf[((nh*32 + l/32)*2 + dh/16)*512 + ((l%32)/8*16 + dh%16)*8 + l%8]
// MODE 1: out-proj epilogue fused with per-column softmax-pool partials.
// ---------------------------------------------------------------------------
template <int MODE>
__global__ __launch_bounds__(256) void gemm_bf16(
    const unsigned short* __restrict__ Ag, const unsigned short* __restrict__ Bg,
    const float* __restrict__ b0, const float* __restrict__ b1,
    const float* __restrict__ b2,
    unsigned short* __restrict__ OutB,
    float* __restrict__ pmO, float* __restrict__ plO, float* __restrict__ psO)
{
    __shared__ unsigned short As[16 * 512];   // 16 KiB
    __shared__ unsigned short Bs[16 * 512];   // 16 KiB

    const int m0 = blockIdx.x * 128;
    const int n0 = blockIdx.y * 128;
    const int tid  = threadIdx.x;
    const int wv   = tid >> 6;
    const int lane = tid & 63;
    const int l15  = lane & 15;
    const int quad = lane >> 4;
    const int wr = (wv & 1) * 64;
    const int wc = (wv >> 1) * 64;

    // staging role: waves 0,1 -> A frags 0-7/8-15; waves 2,3 -> B likewise
    const int isB = wv >> 1;
    const unsigned short* __restrict__ Mg = isB ? Bg : Ag;
    const int mb0 = isB ? n0 : m0;
    unsigned short* Ms = isB ? Bs : As;
    const int fbase = (wv & 1) * 8;

    f32x4 acc[4][4] = {};

    for (int kt = 0; kt < 4; ++kt) {       // K = 256, BK = 64
        __syncthreads();                   // readers of previous tile done
        #pragma unroll
        for (int f = 0; f < 8; ++f) {
            const int fi = fbase + f;      // 0..15
            const int i = fi >> 1, ks = fi & 1;
            load_lds16(Mg + (size_t)(mb0 + i*16 + l15) * 256 + kt*64 + ks*32 + quad*8,
                       Ms + fi * 512);
        }
        __syncthreads();                   // drains vmcnt (async LDS writes done)
        #pragma unroll
        for (int ks = 0; ks < 2; ++ks) {
            bf16x8 af[4], bfr[4];
            #pragma unroll
            for (int i = 0; i < 4; ++i)
                af[i] = *(const bf16x8*)(&As[((((wv & 1)*4 + i)*2) + ks)*512 + lane*8]);
            #pragma unroll
            for (int j = 0; j < 4; ++j)
                bfr[j] = *(const bf16x8*)(&Bs[((((wv >> 1)*4 + j)*2) + ks)*512 + lane*8]);
            #pragma unroll
            for (int i = 0; i < 4; ++i)
                #pragma unroll
                for (int j = 0; j < 4; ++j)
                    acc[i][j] = __builtin_amdgcn_mfma_f32_16x16x32_bf16(
                        af[i], bfr[j], acc[i][j], 0, 0, 0);
        }
    }

    if (MODE == 0) {
        const int mat = n0 >> 8;
        if (mat != 2) {
            const float scale = (mat == 0) ? QSCALE : 1.0f;
            const float* __restrict__ bias = (mat == 0) ? b0 : b1;
            unsigned short* __restrict__ Out = OutB + (size_t)mat * QKVN;
            #pragma unroll
            for (int j = 0; j < 4; ++j) {
                const int c  = n0 + wc + j*16 + l15;
                const int cc = c & 255;
                const int h = cc >> 5, dh = cc & 31;
                const float bv = bias[cc];
                #pragma unroll
                for (int i = 0; i < 4; ++i)
                    #pragma unroll
                    for (int rr = 0; rr < 4; ++rr) {
                        const int r = m0 + wr + i*16 + quad*4 + rr;
                        const int n = r >> 10, l = r & 1023;
                        Out[(((size_t)(n*NHEAD + h)) * LEN + l) * DHD + dh] =
                            f2bf((acc[i][j][rr] + bv) * scale);
                    }
            }
        } else {
            // V: direct fragment-order store (ushort4 over rr -> l%8 run)
            unsigned short* __restrict__ Vf = OutB + 2 * QKVN;
            #pragma unroll
            for (int j = 0; j < 4; ++j) {
                const int c  = n0 + wc + j*16 + l15;
                const int cc = c & 255;
                const int h = cc >> 5, dh = cc & 31;
                const int dhb = dh >> 4, mv = dh & 15;
                const float bv = b2[cc];
                #pragma unroll
                for (int i = 0; i < 4; ++i) {
                    const int r0 = m0 + wr + i*16 + quad*4;   // +rr, rr=0..3
                    const int n = r0 >> 10, l0 = r0 & 1023;
                    const int nh = n*NHEAD + h;
                    const int kb = l0 >> 5;
                    const int qv = (l0 & 31) >> 3, jv0 = l0 & 7;
                    const size_t addr =
                        (((size_t)nh*32 + kb)*2 + dhb)*512 + (qv*16 + mv)*8 + jv0;
                    ushort4 u;
                    u.x = f2bf(acc[i][j][0] + bv);
                    u.y = f2bf(acc[i][j][1] + bv);
                    u.z = f2bf(acc[i][j][2] + bv);
                    u.w = f2bf(acc[i][j][3] + bv);
                    *(ushort4*)(Vf + addr) = u;
                }
            }
        }
    } else {
        // Fused softmax-pool partials over the block's 128 rows (one n).
        const int n    = blockIdx.x >> 3;
        const int tile = blockIdx.x & 7;
        __shared__ float red[4][64];   // [wave][j*16 + l15]

        float bv[4];
        #pragma unroll
        for (int j = 0; j < 4; ++j) bv[j] = b0[n0 + wc + j*16 + l15];
        #pragma unroll
        for (int i = 0; i < 4; ++i)
            #pragma unroll
            for (int j = 0; j < 4; ++j)
                #pragma unroll
                for (int rr = 0; rr < 4; ++rr)
                    acc[i][j][rr] += bv[j];

        float M[4];
        #pragma unroll
        for (int j = 0; j < 4; ++j) {
            float m = -1e30f;
            #pragma unroll
            for (int i = 0; i < 4; ++i)
                #pragma unroll
                for (int rr = 0; rr < 4; ++rr) m = fmaxf(m, acc[i][j][rr]);
            m = fmaxf(m, __shfl_xor(m, 16));
            m = fmaxf(m, __shfl_xor(m, 32));
            M[j] = m;
        }
        if (quad == 0) {
            #pragma unroll
            for (int j = 0; j < 4; ++j) red[wv][j*16 + l15] = M[j];
        }
        __syncthreads();
        #pragma unroll
        for (int j = 0; j < 4; ++j)
            M[j] = fmaxf(red[wv][j*16 + l15], red[wv^1][j*16 + l15]);
        __syncthreads();

        float LE[4], SE[4];
        #pragma unroll
        for (int j = 0; j < 4; ++j) {
            float le = 0.f, se = 0.f;
            #pragma unroll
            for (int i = 0; i < 4; ++i)
                #pragma unroll
                for (int rr = 0; rr < 4; ++rr) {
                    const float z = acc[i][j][rr];
                    const float e = __expf(z - M[j]);
                    le += e; se += z * e;
                }
            le += __shfl_xor(le, 16); le += __shfl_xor(le, 32);
            se += __shfl_xor(se, 16); se += __shfl_xor(se, 32);
            LE[j] = le; SE[j] = se;
        }
        if (quad == 0) {
            #pragma unroll
            for (int j = 0; j < 4; ++j) red[wv][j*16 + l15] = LE[j];
        }
        __syncthreads();
        float LEp[4];
        #pragma unroll
        for (int j = 0; j < 4; ++j) LEp[j] = red[wv^1][j*16 + l15];
        __syncthreads();
        if (quad == 0) {
            #pragma unroll
            for (int j = 0; j < 4; ++j) red[wv][j*16 + l15] = SE[j];
        }
        __syncthreads();
        float SEp[4];
        #pragma unroll
        for (int j = 0; j < 4; ++j) SEp[j] = red[wv^1][j*16 + l15];

        if ((wv & 1) == 0 && quad == 0) {
            #pragma unroll
            for (int j = 0; j < 4; ++j) {
                const int c = n0 + wc + j*16 + l15;
                const size_t o = ((size_t)n*8 + tile)*256 + c;
                pmO[o] = M[j];
                plO[o] = LE[j] + LEp[j];
                psO[o] = SE[j] + SEp[j];
            }
        }
    }
}

// ---------------------------------------------------------------------------
// Kernel 2: MFMA flash attention, fixed-max softmax, S^T formulation.
// 64 Q-rows PER WAVE (4 groups of 16), 256 rows/block: K/V operand traffic
// amortized 4x vs R7. K and frag-order V read DIRECT from global (each load
// = contiguous 1KB/wave), both prefetched one 64-key tile ahead. Only the
// P round-trip uses LDS (wave-private, barrier-free — R5/R7 HW-verified).
// P truncated to bf16; l accumulated from truncated values (bias cancels).
// ---------------------------------------------------------------------------
#define LDPk 72    // P^T leading dim bf16 (64 data + 8 pad)
__global__ __launch_bounds__(256) void attn_mfma(
    const unsigned short* __restrict__ Qg_, const unsigned short* __restrict__ Kg_,
    const unsigned short* __restrict__ Vf_, unsigned short* __restrict__ Aout)
{
    __shared__ unsigned short Pb[4][16 * LDPk]; // 9216 B total

    const int nh = blockIdx.y;
    const int n  = nh >> 3, h = nh & 7;
    const int q0 = blockIdx.x * 256;
    const int tid  = threadIdx.x;
    const int wv   = tid >> 6;
    const int lane = tid & 63;
    const int l15  = lane & 15;
    const int quad = lane >> 4;

    const unsigned short* __restrict__ Qg = Qg_ + (size_t)nh * LEN * DHD;
    const unsigned short* __restrict__ Kg = Kg_ + (size_t)nh * LEN * DHD;
    const unsigned short* __restrict__ Vf = Vf_ + (size_t)nh * 32768;

    // Q fragments (B-operand), 4 groups of 16 rows
    bf16x8 qf[4];
    #pragma unroll
    for (int g = 0; g < 4; ++g)
        qf[g] = *(const bf16x8*)(Qg + (size_t)(q0 + wv*64 + g*16 + l15) * DHD + quad*8);

    f32x4 oA[4] = {{0.f,0.f,0.f,0.f},{0.f,0.f,0.f,0.f},{0.f,0.f,0.f,0.f},{0.f,0.f,0.f,0.f}};
    f32x4 oB[4] = {{0.f,0.f,0.f,0.f},{0.f,0.f,0.f,0.f},{0.f,0.f,0.f,0.f},{0.f,0.f,0.f,0.f}};
    float l_acc[4] = {0.f, 0.f, 0.f, 0.f};

    const unsigned short* __restrict__ kbase = Kg + (size_t)l15 * DHD + quad*8;
    const unsigned short* __restrict__ vbase = Vf + lane*8;

    // prefetch tile 0
    bf16x8 kf[4], vv[4];
    #pragma unroll
    for (int s = 0; s < 4; ++s) kf[s] = *(const bf16x8*)(kbase + (size_t)(s*16) * DHD);
    #pragma unroll
    for (int j = 0; j < 4; ++j) vv[j] = *(const bf16x8*)(vbase + j*512);

    unsigned short* __restrict__ Pw = &Pb[wv][0];

    for (int t = 0; t < 16; ++t) {
        bf16x8 kn[4], vn[4];
        if (t < 15) {
            #pragma unroll
            for (int s = 0; s < 4; ++s)
                kn[s] = *(const bf16x8*)(kbase + (size_t)((t+1)*64 + s*16) * DHD);
            #pragma unroll
            for (int j = 0; j < 4; ++j)
                vn[j] = *(const bf16x8*)(vbase + ((t+1)*4 + j)*512);
        }
        #pragma unroll
        for (int g = 0; g < 4; ++g) {
            // S^T = K.Q^T: 4 subtiles of 16 keys
            f32x4 st[4];
            #pragma unroll
            for (int s = 0; s < 4; ++s) {
                f32x4 z = {0.f, 0.f, 0.f, 0.f};
                st[s] = __builtin_amdgcn_mfma_f32_16x16x32_bf16(kf[s], qf[g], z, 0, 0, 0);
            }
            // p = exp(s), truncate to bf16; l from truncated values (consistent)
            float lg = 0.f;
            #pragma unroll
            for (int s = 0; s < 4; ++s) {
                const unsigned int a0 = __float_as_uint(__expf(st[s][0])) & 0xffff0000u;
                const unsigned int a1 = __float_as_uint(__expf(st[s][1])) & 0xffff0000u;
                const unsigned int a2 = __float_as_uint(__expf(st[s][2])) & 0xffff0000u;
                const unsigned int a3 = __float_as_uint(__expf(st[s][3])) & 0xffff0000u;
                lg += (__uint_as_float(a0) + __uint_as_float(a1))
                    + (__uint_as_float(a2) + __uint_as_float(a3));
                uint2 pk;
                pk.x = (a0 >> 16) | a1;
                pk.y = (a2 >> 16) | a3;
                *(uint2*)(&Pw[l15*LDPk + s*16 + quad*4]) = pk;
            }
            l_acc[g] += lg;
            // O^T += Vfrag x P^T (wave-private P; in-order DS, no barrier)
            #pragma unroll
            for (int kk = 0; kk < 2; ++kk) {
                bf16x8 pf = *(const bf16x8*)(&Pw[l15*LDPk + kk*32 + quad*8]);
                oA[g] = __builtin_amdgcn_mfma_f32_16x16x32_bf16(vv[kk*2+0], pf, oA[g], 0, 0, 0);
                oB[g] = __builtin_amdgcn_mfma_f32_16x16x32_bf16(vv[kk*2+1], pf, oB[g], 0, 0, 0);
            }
        }
        if (t < 15) {
            #pragma unroll
            for (int s = 0; s < 4; ++s) kf[s] = kn[s];
            #pragma unroll
            for (int j = 0; j < 4; ++j) vv[j] = vn[j];
        }
    }

    // reduce l across the 4 quad-lanes holding each q
    float linv[4];
    #pragma unroll
    for (int g = 0; g < 4; ++g) {
        float tsum = l_acc[g];
        tsum += __shfl_xor(tsum, 16);
        tsum += __shfl_xor(tsum, 32);
        linv[g] = 1.f / tsum;
    }

    // transpose O^T -> O through wave-private LDS (sequential per group)
    float* __restrict__ Tw = (float*)&Pb[wv][0];   // 16 x 36 fp32 = 2304 B
    const int qr = lane >> 2, c8 = (lane & 3) * 8;
    #pragma unroll
    for (int g = 0; g < 4; ++g) {
        #pragma unroll
        for (int r = 0; r < 4; ++r) {
            Tw[l15*36 + quad*4 + r]      = oA[g][r] * linv[g];
            Tw[l15*36 + 16 + quad*4 + r] = oB[g][r] * linv[g];
        }
        float4 r0 = *(const float4*)(&Tw[qr*36 + c8]);
        float4 r1 = *(const float4*)(&Tw[qr*36 + c8 + 4]);
        unsigned short* dst =
            Aout + ((size_t)(n*LEN + q0 + wv*64 + g*16 + qr)) * DDIM + h*DHD + c8;
        ushort4 u0, u1;
        u0.x = f2bf(r0.x); u0.y = f2bf(r0.y); u0.z = f2bf(r0.z); u0.w = f2bf(r0.w);
        u1.x = f2bf(r1.x); u1.y = f2bf(r1.y); u1.z = f2bf(r1.z); u1.w = f2bf(r1.w);
        *(ushort4*)(dst)     = u0;
        *(ushort4*)(dst + 4) = u1;
    }
}

// ---------------------------------------------------------------------------
// Kernel 3: merge 8 per-tile pool partials per (n,d), write [B,S,D] output.
// ---------------------------------------------------------------------------
__global__ __launch_bounds__(256) void pool_merge(
    const float* __restrict__ pm, const float* __restrict__ pl,
    const float* __restrict__ ps, float* __restrict__ out)
{
    const int n = blockIdx.x;
    const int d = threadIdx.x;
    float M = -1e30f;
    #pragma unroll
    for (int t = 0; t < 8; ++t) M = fmaxf(M, pm[((size_t)n*8 + t)*256 + d]);
    float L = 0.f, S = 0.f;
    #pragma unroll
    for (int t = 0; t < 8; ++t) {
        const size_t idx = ((size_t)n*8 + t)*256 + d;
        const float w = __expf(pm[idx] - M);
        L += pl[idx] * w;
        S += ps[idx] * w;
    }
    out[n*256 + d] = S / L;
}

// ---------------------------------------------------------------------------
extern "C" void kernel_launch(void* const* d_in, const int* in_sizes, int n_in,
                              void* d_out, int out_size, void* d_ws, size_t ws_size,
                              hipStream_t stream)
{
    const float* x  = (const float*)d_in[0];
    const float* Wq = (const float*)d_in[1];
    const float* bq = (const float*)d_in[2];
    const float* Wk = (const float*)d_in[3];
    const float* bk = (const float*)d_in[4];
    const float* Wv = (const float*)d_in[5];
    const float* bv = (const float*)d_in[6];
    const float* Wo = (const float*)d_in[7];
    const float* bo = (const float*)d_in[8];
    float* out = (float*)d_out;

    char* base = (char*)d_ws;
    unsigned short* Xbf  = (unsigned short*)(base);                 //  8,388,608 B
    unsigned short* Qb   = (unsigned short*)(base +  8388608);      //  8,388,608
    // Kb = Qb + QKVN (implicit), Vfrag = Qb + 2*QKVN at +25165824
    unsigned short* Vfrag= (unsigned short*)(base + 25165824);      //  8,388,608
    unsigned short* attnb= (unsigned short*)(base + 41943040);      //  8,388,608
    unsigned short* Wbf  = (unsigned short*)(base + 50331648);      //    524,288
    float* pm = (float*)(base + 50855936);                          //    131,072
    float* pl = (float*)(base + 50987008);                          //    131,072
    float* ps = (float*)(base + 51118080);                          //    131,072
    const size_t need_bytes = 51249152;
    if (ws_size < need_bytes) return;

    convert_bf16<<<4352, 256, 0, stream>>>(x, Wq, Wk, Wv, Wo, Xbf, Wbf);
    gemm_bf16<0><<<dim3(ROWS/128, 6), 256, 0, stream>>>(
        Xbf, Wbf, bq, bk, bv, Qb, nullptr, nullptr, nullptr);
    attn_mfma<<<dim3(LEN/256, N_SEQ*NHEAD), 256, 0, stream>>>(
        Qb, Qb + QKVN, Vfrag, attnb);
    gemm_bf16<1><<<dim3(ROWS/128, 2), 256, 0, stream>>>(
        attnb, Wbf + (size_t)768*256, bo, nullptr, nullptr, nullptr, pm, pl, ps);
    pool_merge<<<16, 256, 0, stream>>>(pm, pl, ps, out);
}

// Round 9
// 139.058 us; speedup vs baseline: 1.4344x; 1.0128x over previous
//
#include <hip/hip_runtime.h>
#include <math.h>

// Problem constants: B=4,S=4 -> N=16 sequences
#define N_SEQ 16
#define LEN   1024
#define FDIM  256
#define DDIM  256
#define NHEAD 8
#define DHD   32
#define ROWS  (N_SEQ * LEN)          // 16384
#define QSCALE 0.17677669529663687f  // 1/sqrt(32)
#define LOG2E  1.4426950408889634f
#define QKVN  ((size_t)N_SEQ * NHEAD * LEN * DHD)   // 4,194,304 elems

typedef __attribute__((ext_vector_type(8))) short bf16x8;  // 8 bf16 in 4 VGPRs
typedef __attribute__((ext_vector_type(4))) float f32x4;

__device__ __forceinline__ unsigned short f2bf(float f) {
    unsigned int u = __float_as_uint(f);
    unsigned int r = u + 0x7fffu + ((u >> 16) & 1u);   // RNE
    return (unsigned short)(r >> 16);
}

// 2^x via raw v_exp_f32 (Q is pre-scaled by 1/sqrt(32)*log2e)
#if __has_builtin(__builtin_amdgcn_exp2f)
#define EXP2F(x) __builtin_amdgcn_exp2f(x)
#else
#define EXP2F(x) __expf((x) * 0.6931471805599453f)
#endif

// pack hi16(p0), hi16(p1) -> one dword via v_perm_b32 (truncation to bf16)
__device__ __forceinline__ unsigned int pack_bf16_trunc(float p0, float p1) {
    return __builtin_amdgcn_perm(__float_as_uint(p1), __float_as_uint(p0), 0x07060302u);
}

// async global->LDS, 16B per lane; LDS dest = uniform base + lane*16
__device__ __forceinline__ void load_lds16(const void* g, void* l) {
    __builtin_amdgcn_global_load_lds(
        (const __attribute__((address_space(1))) unsigned int*)g,
        (__attribute__((address_space(3))) unsigned int*)l, 16, 0, 0);
}

// ---------------------------------------------------------------------------
// Kernel 0: fp32 -> bf16 convert for X and the 4 weight matrices.
// ---------------------------------------------------------------------------
__global__ __launch_bounds__(256) void convert_bf16(
    const float* __restrict__ X,
    const float* __restrict__ Wq, const float* __restrict__ Wk,
    const float* __restrict__ Wv, const float* __restrict__ Wo,
    unsigned short* __restrict__ Xbf, unsigned short* __restrict__ Wbf)
{
    const size_t idx4 = ((size_t)blockIdx.x * 256 + threadIdx.x) * 4;
    const float* src;
    unsigned short* dst;
    if (idx4 < (size_t)ROWS * FDIM) {
        src = X + idx4;
        dst = Xbf + idx4;
    } else {
        const size_t wi = idx4 - (size_t)ROWS * FDIM;   // [0, 262144)
        const int w = (int)(wi >> 16);
        const size_t off = wi & 65535;
        const float* Ws[4] = {Wq, Wk, Wv, Wo};
        src = Ws[w] + off;
        dst = Wbf + wi;
    }
    float4 v = *(const float4*)src;
    ushort4 u;
    u.x = f2bf(v.x); u.y = f2bf(v.y); u.z = f2bf(v.z); u.w = f2bf(v.w);
    *(ushort4*)dst = u;
}

// ---------------------------------------------------------------------------
// Kernel 1: bf16 MFMA GEMM, 128x128 tile, BK=64, 4 waves, global_load_lds
// staging into fragment-order LDS (R6-verified).
// MODE 0, mat<2 (Q,K): SWAPPED operands (A=W rows, B=X rows) so the C-layout
//   puts 4 consecutive output channels in acc[..][rr] -> ushort4 head-split
//   stores. Q pre-scale includes log2(e) for the exp2-based softmax.
// MODE 0, mat==2 (V): original orientation, direct A-fragment-order store.
// MODE 1: out-proj epilogue fused with per-column softmax-pool partials.
// ---------------------------------------------------------------------------
template <int MODE>
__global__ __launch_bounds__(256) void gemm_bf16(
    const unsigned short* __restrict__ Ag, const unsigned short* __restrict__ Bg,
    const float* __restrict__ b0, const float* __restrict__ b1,
    const float* __restrict__ b2,
    unsigned short* __restrict__ OutB,
    float* __restrict__ pmO, float* __restrict__ plO, float* __restrict__ psO)
{
    __shared__ unsigned short As[16 * 512];   // 16 KiB
    __shared__ unsigned short Bs[16 * 512];   // 16 KiB

    const int tid  = threadIdx.x;
    const int wv   = tid >> 6;
    const int lane = tid & 63;
    const int l15  = lane & 15;
    const int quad = lane >> 4;
    const int wr = (wv & 1) * 64;
    const int wc = (wv >> 1) * 64;

    int mat = 0, cb = 0, abase, bbase;
    const unsigned short* __restrict__ Astage;
    const unsigned short* __restrict__ Bstage;
    if (MODE == 0) {
        mat = blockIdx.y >> 1;
        cb  = (blockIdx.y & 1) * 128;
        if (mat < 2) {  // swapped: A = weights (channels), B = X (rows)
            Astage = Bg + (size_t)mat * 65536; abase = cb;
            Bstage = Ag;                       bbase = blockIdx.x * 128;
        } else {        // V: original orientation
            Astage = Ag;                       abase = blockIdx.x * 128;
            Bstage = Bg + (size_t)2 * 65536;   bbase = cb;
        }
    } else {
        Astage = Ag; abase = blockIdx.x * 128;
        Bstage = Bg; bbase = blockIdx.y * 128;
    }

    // staging role: waves 0,1 -> A frags 0-7/8-15; waves 2,3 -> B likewise
    const int isB = wv >> 1;
    const unsigned short* __restrict__ Mg = isB ? Bstage : Astage;
    const int mb0 = isB ? bbase : abase;
    unsigned short* Ms = isB ? Bs : As;
    const int fbase = (wv & 1) * 8;

    f32x4 acc[4][4] = {};

    for (int kt = 0; kt < 4; ++kt) {       // K = 256, BK = 64
        __syncthreads();                   // readers of previous tile done
        #pragma unroll
        for (int f = 0; f < 8; ++f) {
            const int fi = fbase + f;      // 0..15
            const int i = fi >> 1, ks = fi & 1;
            load_lds16(Mg + (size_t)(mb0 + i*16 + l15) * 256 + kt*64 + ks*32 + quad*8,
                       Ms + fi * 512);
        }
        __syncthreads();                   // drains vmcnt (async LDS writes done)
        #pragma unroll
        for (int ks = 0; ks < 2; ++ks) {
            bf16x8 af[4], bfr[4];
            #pragma unroll
            for (int i = 0; i < 4; ++i)
                af[i] = *(const bf16x8*)(&As[((((wv & 1)*4 + i)*2) + ks)*512 + lane*8]);
            #pragma unroll
            for (int j = 0; j < 4; ++j)
                bfr[j] = *(const bf16x8*)(&Bs[((((wv >> 1)*4 + j)*2) + ks)*512 + lane*8]);
            #pragma unroll
            for (int i = 0; i < 4; ++i)
                #pragma unroll
                for (int j = 0; j < 4; ++j)
                    acc[i][j] = __builtin_amdgcn_mfma_f32_16x16x32_bf16(
                        af[i], bfr[j], acc[i][j], 0, 0, 0);
        }
    }

    if (MODE == 0) {
        if (mat < 2) {
            // Q/K: acc rows = channels, cols = x-rows. ushort4 stores.
            const float scale = (mat == 0) ? QSCALE * LOG2E : 1.0f;
            const float* __restrict__ bias = (mat == 0) ? b0 : b1;
            unsigned short* __restrict__ Out = OutB + (size_t)mat * QKVN;
            #pragma unroll
            for (int i = 0; i < 4; ++i) {
                const int c0 = cb + wr + i*16 + quad*4;   // channel, %4==0
                const int h = c0 >> 5, dh = c0 & 31;
                const float4 bv4 = *(const float4*)(bias + c0);
                #pragma unroll
                for (int j = 0; j < 4; ++j) {
                    const int r = bbase + wc + j*16 + l15;
                    const int n = r >> 10, l = r & 1023;
                    ushort4 u;
                    u.x = f2bf((acc[i][j][0] + bv4.x) * scale);
                    u.y = f2bf((acc[i][j][1] + bv4.y) * scale);
                    u.z = f2bf((acc[i][j][2] + bv4.z) * scale);
                    u.w = f2bf((acc[i][j][3] + bv4.w) * scale);
                    *(ushort4*)(Out + ((size_t)(n*NHEAD + h) * LEN + l) * DHD + dh) = u;
                }
            }
        } else {
            // V: direct fragment-order store (ushort4 over rr -> l%8 run)
            unsigned short* __restrict__ Vf = OutB + 2 * QKVN;
            #pragma unroll
            for (int j = 0; j < 4; ++j) {
                const int cc = cb + wc + j*16 + l15;      // mat-local channel
                const int h = cc >> 5, dh = cc & 31;
                const int dhb = dh >> 4, mv = dh & 15;
                const float bv = b2[cc];
                #pragma unroll
                for (int i = 0; i < 4; ++i) {
                    const int r0 = abase + wr + i*16 + quad*4;   // +rr, rr=0..3
                    const int n = r0 >> 10, l0 = r0 & 1023;
                    const int nh = n*NHEAD + h;
                    const int kb = l0 >> 5;
                    const int qv = (l0 & 31) >> 3, jv0 = l0 & 7;
                    const size_t addr =
                        (((size_t)nh*32 + kb)*2 + dhb)*512 + (qv*16 + mv)*8 + jv0;
                    ushort4 u;
                    u.x = f2bf(acc[i][j][0] + bv);
                    u.y = f2bf(acc[i][j][1] + bv);
                    u.z = f2bf(acc[i][j][2] + bv);
                    u.w = f2bf(acc[i][j][3] + bv);
                    *(ushort4*)(Vf + addr) = u;
                }
            }
        }
    } else {
        // Fused softmax-pool partials over the block's 128 rows (one n).
        const int n    = blockIdx.x >> 3;
        const int tile = blockIdx.x & 7;
        __shared__ float red[4][64];   // [wave][j*16 + l15]

        float bv[4];
        #pragma unroll
        for (int j = 0; j < 4; ++j) bv[j] = b0[bbase + wc + j*16 + l15];
        #pragma unroll
        for (int i = 0; i < 4; ++i)
            #pragma unroll
            for (int j = 0; j < 4; ++j)
                #pragma unroll
                for (int rr = 0; rr < 4; ++rr)
                    acc[i][j][rr] += bv[j];

        float M[4];
        #pragma unroll
        for (int j = 0; j < 4; ++j) {
            float m = -1e30f;
            #pragma unroll
            for (int i = 0; i < 4; ++i)
                #pragma unroll
                for (int rr = 0; rr < 4; ++rr) m = fmaxf(m, acc[i][j][rr]);
            m = fmaxf(m, __shfl_xor(m, 16));
            m = fmaxf(m, __shfl_xor(m, 32));
            M[j] = m;
        }
        if (quad == 0) {
            #pragma unroll
            for (int j = 0; j < 4; ++j) red[wv][j*16 + l15] = M[j];
        }
        __syncthreads();
        #pragma unroll
        for (int j = 0; j < 4; ++j)
            M[j] = fmaxf(red[wv][j*16 + l15], red[wv^1][j*16 + l15]);
        __syncthreads();

        float LE[4], SE[4];
        #pragma unroll
        for (int j = 0; j < 4; ++j) {
            float le = 0.f, se = 0.f;
            #pragma unroll
            for (int i = 0; i < 4; ++i)
                #pragma unroll
                for (int rr = 0; rr < 4; ++rr) {
                    const float z = acc[i][j][rr];
                    const float e = __expf(z - M[j]);
                    le += e; se += z * e;
                }
            le += __shfl_xor(le, 16); le += __shfl_xor(le, 32);
            se += __shfl_xor(se, 16); se += __shfl_xor(se, 32);
            LE[j] = le; SE[j] = se;
        }
        if (quad == 0) {
            #pragma unroll
            for (int j = 0; j < 4; ++j) red[wv][j*16 + l15] = LE[j];
        }
        __syncthreads();
        float LEp[4];
        #pragma unroll
        for (int j = 0; j < 4; ++j) LEp[j] = red[wv^1][j*16 + l15];
        __syncthreads();
        if (quad == 0) {
            #pragma unroll
            for (int j = 0; j < 4; ++j) red[wv][j*16 + l15] = SE[j];
        }
        __syncthreads();
        float SEp[4];
        #pragma unroll
        for (int j = 0; j < 4; ++j) SEp[j] = red[wv^1][j*16 + l15];

        if ((wv & 1) == 0 && quad == 0) {
            #pragma unroll
            for (int j = 0; j < 4; ++j) {
                const int c = bbase + wc + j*16 + l15;
                const size_t o = ((size_t)n*8 + tile)*256 + c;
                pmO[o] = M[j];
                plO[o] = LE[j] + LEp[j];
                psO[o] = SE[j] + SEp[j];
            }
        }
    }
}

// ---------------------------------------------------------------------------
// Kernel 2: MFMA flash attention, fixed-max softmax via exp2 (log2e folded
// into Q), S^T formulation, 64 Q-rows/wave. K + frag-order V direct from
// global, prefetched one tile. P double-buffered in wave-private LDS with
// PV lagged one group: read P(g-1) (no pending RAW) BEFORE writing P(g).
// P packed to bf16 via v_perm (1 op/pair); l summed from raw fp32 exps.
// ---------------------------------------------------------------------------
#define LDPk 72    // P^T leading dim bf16 (64 data + 8 pad)
__global__ __launch_bounds__(256) void attn_mfma(
    const unsigned short* __restrict__ Qg_, const unsigned short* __restrict__ Kg_,
    const unsigned short* __restrict__ Vf_, unsigned short* __restrict__ Aout)
{
    __shared__ unsigned short Pb[4][2][16 * LDPk]; // 18432 B total

    const int nh = blockIdx.y;
    const int n  = nh >> 3, h = nh & 7;
    const int q0 = blockIdx.x * 256;
    const int tid  = threadIdx.x;
    const int wv   = tid >> 6;
    const int lane = tid & 63;
    const int l15  = lane & 15;
    const int quad = lane >> 4;

    const unsigned short* __restrict__ Qg = Qg_ + (size_t)nh * LEN * DHD;
    const unsigned short* __restrict__ Kg = Kg_ + (size_t)nh * LEN * DHD;
    const unsigned short* __restrict__ Vf = Vf_ + (size_t)nh * 32768;

    // Q fragments (B-operand), 4 groups of 16 rows
    bf16x8 qf[4];
    #pragma unroll
    for (int g = 0; g < 4; ++g)
        qf[g] = *(const bf16x8*)(Qg + (size_t)(q0 + wv*64 + g*16 + l15) * DHD + quad*8);

    f32x4 oA[4] = {{0.f,0.f,0.f,0.f},{0.f,0.f,0.f,0.f},{0.f,0.f,0.f,0.f},{0.f,0.f,0.f,0.f}};
    f32x4 oB[4] = {{0.f,0.f,0.f,0.f},{0.f,0.f,0.f,0.f},{0.f,0.f,0.f,0.f},{0.f,0.f,0.f,0.f}};
    float l_acc[4] = {0.f, 0.f, 0.f, 0.f};

    const unsigned short* __restrict__ kbase = Kg + (size_t)l15 * DHD + quad*8;
    const unsigned short* __restrict__ vbase = Vf + lane*8;

    // prefetch tile 0
    bf16x8 kf[4], vv[4];
    #pragma unroll
    for (int s = 0; s < 4; ++s) kf[s] = *(const bf16x8*)(kbase + (size_t)(s*16) * DHD);
    #pragma unroll
    for (int j = 0; j < 4; ++j) vv[j] = *(const bf16x8*)(vbase + j*512);

    unsigned short* __restrict__ Pw0 = &Pb[wv][0][0];
    unsigned short* __restrict__ Pw1 = &Pb[wv][1][0];

    for (int t = 0; t < 16; ++t) {
        bf16x8 kn[4], vn[4];
        if (t < 15) {
            #pragma unroll
            for (int s = 0; s < 4; ++s)
                kn[s] = *(const bf16x8*)(kbase + (size_t)((t+1)*64 + s*16) * DHD);
            #pragma unroll
            for (int j = 0; j < 4; ++j)
                vn[j] = *(const bf16x8*)(vbase + ((t+1)*4 + j)*512);
        }
        #pragma unroll
        for (int g = 0; g < 4; ++g) {
            unsigned short* __restrict__ Pcur  = (g & 1) ? Pw1 : Pw0;
            unsigned short* __restrict__ Pprev = (g & 1) ? Pw0 : Pw1;
            // S^T = K.Q^T: 4 subtiles of 16 keys
            f32x4 st[4];
            #pragma unroll
            for (int s = 0; s < 4; ++s) {
                f32x4 z = {0.f, 0.f, 0.f, 0.f};
                st[s] = __builtin_amdgcn_mfma_f32_16x16x32_bf16(kf[s], qf[g], z, 0, 0, 0);
            }
            // p = 2^s (log2e pre-folded); pack via v_perm; l from raw fp32
            uint2 pk[4];
            float lg = 0.f;
            #pragma unroll
            for (int s = 0; s < 4; ++s) {
                const float p0 = EXP2F(st[s][0]);
                const float p1 = EXP2F(st[s][1]);
                const float p2 = EXP2F(st[s][2]);
                const float p3 = EXP2F(st[s][3]);
                lg += (p0 + p1) + (p2 + p3);
                pk[s].x = pack_bf16_trunc(p0, p1);
                pk[s].y = pack_bf16_trunc(p2, p3);
            }
            l_acc[g] += lg;
            // read previous group's P first (no pending RAW), then write ours
            bf16x8 pf0, pf1;
            if (g > 0) {
                pf0 = *(const bf16x8*)(&Pprev[l15*LDPk + 0*32 + quad*8]);
                pf1 = *(const bf16x8*)(&Pprev[l15*LDPk + 1*32 + quad*8]);
            }
            #pragma unroll
            for (int s = 0; s < 4; ++s)
                *(uint2*)(&Pcur[l15*LDPk + s*16 + quad*4]) = pk[s];
            if (g > 0) {
                oA[g-1] = __builtin_amdgcn_mfma_f32_16x16x32_bf16(vv[0], pf0, oA[g-1], 0, 0, 0);
                oB[g-1] = __builtin_amdgcn_mfma_f32_16x16x32_bf16(vv[1], pf0, oB[g-1], 0, 0, 0);
                oA[g-1] = __builtin_amdgcn_mfma_f32_16x16x32_bf16(vv[2], pf1, oA[g-1], 0, 0, 0);
                oB[g-1] = __builtin_amdgcn_mfma_f32_16x16x32_bf16(vv[3], pf1, oB[g-1], 0, 0, 0);
            }
        }
        // tail: group 3 (buffer 1)
        {
            bf16x8 pf0 = *(const bf16x8*)(&Pw1[l15*LDPk + 0*32 + quad*8]);
            bf16x8 pf1 = *(const bf16x8*)(&Pw1[l15*LDPk + 1*32 + quad*8]);
            oA[3] = __builtin_amdgcn_mfma_f32_16x16x32_bf16(vv[0], pf0, oA[3], 0, 0, 0);
            oB[3] = __builtin_amdgcn_mfma_f32_16x16x32_bf16(vv[1], pf0, oB[3], 0, 0, 0);
            oA[3] = __builtin_amdgcn_mfma_f32_16x16x32_bf16(vv[2], pf1, oA[3], 0, 0, 0);
            oB[3] = __builtin_amdgcn_mfma_f32_16x16x32_bf16(vv[3], pf1, oB[3], 0, 0, 0);
        }
        if (t < 15) {
            #pragma unroll
            for (int s = 0; s < 4; ++s) kf[s] = kn[s];
            #pragma unroll
            for (int j = 0; j < 4; ++j) vv[j] = vn[j];
        }
    }

    // reduce l across the 4 quad-lanes holding each q
    float linv[4];
    #pragma unroll
    for (int g = 0; g < 4; ++g) {
        float tsum = l_acc[g];
        tsum += __shfl_xor(tsum, 16);
        tsum += __shfl_xor(tsum, 32);
        linv[g] = 1.f / tsum;
    }

    // transpose O^T -> O through wave-private LDS (sequential per group)
    float* __restrict__ Tw = (float*)&Pb[wv][0][0];   // 16 x 36 fp32 = 2304 B
    const int qr = lane >> 2, c8 = (lane & 3) * 8;
    #pragma unroll
    for (int g = 0; g < 4; ++g) {
        #pragma unroll
        for (int r = 0; r < 4; ++r) {
            Tw[l15*36 + quad*4 + r]      = oA[g][r] * linv[g];
            Tw[l15*36 + 16 + quad*4 + r] = oB[g][r] * linv[g];
        }
        float4 r0 = *(const float4*)(&Tw[qr*36 + c8]);
        float4 r1 = *(const float4*)(&Tw[qr*36 + c8 + 4]);
        unsigned short* dst =
            Aout + ((size_t)(n*LEN + q0 + wv*64 + g*16 + qr)) * DDIM + h*DHD + c8;
        ushort4 u0, u1;
        u0.x = f2bf(r0.x); u0.y = f2bf(r0.y); u0.z = f2bf(r0.z); u0.w = f2bf(r0.w);
        u1.x = f2bf(r1.x); u1.y = f2bf(r1.y); u1.z = f2bf(r1.z); u1.w = f2bf(r1.w);
        *(ushort4*)(dst)     = u0;
        *(ushort4*)(dst + 4) = u1;
    }
}

// ---------------------------------------------------------------------------
// Kernel 3: merge 8 per-tile pool partials per (n,d), write [B,S,D] output.
// ---------------------------------------------------------------------------
__global__ __launch_bounds__(256) void pool_merge(
    const float* __restrict__ pm, const float* __restrict__ pl,
    const float* __restrict__ ps, float* __restrict__ out)
{
    const int n = blockIdx.x;
    const int d = threadIdx.x;
    float M = -1e30f;
    #pragma unroll
    for (int t = 0; t < 8; ++t) M = fmaxf(M, pm[((size_t)n*8 + t)*256 + d]);
    float L = 0.f, S = 0.f;
    #pragma unroll
    for (int t = 0; t < 8; ++t) {
        const size_t idx = ((size_t)n*8 + t)*256 + d;
        const float w = __expf(pm[idx] - M);
        L += pl[idx] * w;
        S += ps[idx] * w;
    }
    out[n*256 + d] = S / L;
}

// ---------------------------------------------------------------------------
extern "C" void kernel_launch(void* const* d_in, const int* in_sizes, int n_in,
                              void* d_out, int out_size, void* d_ws, size_t ws_size,
                              hipStream_t stream)
{
    const float* x  = (const float*)d_in[0];
    const float* Wq = (const float*)d_in[1];
    const float* bq = (const float*)d_in[2];
    const float* Wk = (const float*)d_in[3];
    const float* bk = (const float*)d_in[4];
    const float* Wv = (const float*)d_in[5];
    const float* bv = (const float*)d_in[6];
    const float* Wo = (const float*)d_in[7];
    const float* bo = (const float*)d_in[8];
    float* out = (float*)d_out;

    char* base = (char*)d_ws;
    unsigned short* Xbf  = (unsigned short*)(base);                 //  8,388,608 B
    unsigned short* Qb   = (unsigned short*)(base +  8388608);      //  8,388,608
    // Kb = Qb + QKVN (implicit), Vfrag = Qb + 2*QKVN at +25165824
    unsigned short* Vfrag= (unsigned short*)(base + 25165824);      //  8,388,608
    unsigned short* attnb= (unsigned short*)(base + 41943040);      //  8,388,608
    unsigned short* Wbf  = (unsigned short*)(base + 50331648);      //    524,288
    float* pm = (float*)(base + 50855936);                          //    131,072
    float* pl = (float*)(base + 50987008);                          //    131,072
    float* ps = (float*)(base + 51118080);                          //    131,072
    const size_t need_bytes = 51249152;
    if (ws_size < need_bytes) return;

    convert_bf16<<<4352, 256, 0, stream>>>(x, Wq, Wk, Wv, Wo, Xbf, Wbf);
    gemm_bf16<0><<<dim3(ROWS/128, 6), 256, 0, stream>>>(
        Xbf, Wbf, bq, bk, bv, Qb, nullptr, nullptr, nullptr);
    attn_mfma<<<dim3(LEN/256, N_SEQ*NHEAD), 256, 0, stream>>>(
        Qb, Qb + QKVN, Vfrag, attnb);
    gemm_bf16<1><<<dim3(ROWS/128, 2), 256, 0, stream>>>(
        attnb, Wbf + (size_t)768*256, bo, nullptr, nullptr, nullptr, pm, pl, ps);
    pool_merge<<<16, 256, 0, stream>>>(pm, pl, ps, out);
}